// Round 1
// baseline (1110.076 us; speedup 1.0000x reference)
//
#include <hip/hip_runtime.h>
#include <hip/hip_bf16.h>
#include <cstdint>

#define D_MODEL 1024
#define N_HEADS 16
#define D_HEAD  64
#define BATCH   2
#define SEQ     2048
#define ROWS    (BATCH*SEQ)   // 4096
#define BH      (BATCH*N_HEADS) // 32

typedef __bf16 bf16_t;
typedef __bf16 bf16x8 __attribute__((ext_vector_type(8)));
typedef float  f32x4  __attribute__((ext_vector_type(4)));

// async global->LDS, 16B per lane; LDS dest must be wave-uniform base (HW adds lane*16)
__device__ __forceinline__ void gload_lds16(const void* g, void* l) {
  __builtin_amdgcn_global_load_lds(
      (__attribute__((address_space(1))) void*)const_cast<void*>(g),
      (__attribute__((address_space(3))) void*)l, 16, 0, 0);
}

// ---------------- fp32 -> bf16 elementwise (8/thread) ----------------
__global__ __launch_bounds__(256)
void cvt_bf16(const float* __restrict__ in, bf16_t* __restrict__ out, int n8) {
  int i = blockIdx.x * 256 + threadIdx.x;
  if (i >= n8) return;
  const f32x4* src = (const f32x4*)in + (size_t)i * 2;
  f32x4 a = src[0], b = src[1];
  bf16x8 o;
  o[0]=(bf16_t)a[0]; o[1]=(bf16_t)a[1]; o[2]=(bf16_t)a[2]; o[3]=(bf16_t)a[3];
  o[4]=(bf16_t)b[0]; o[5]=(bf16_t)b[1]; o[6]=(bf16_t)b[2]; o[7]=(bf16_t)b[3];
  ((bf16x8*)out)[i] = o;
}

// ---------------- generic bt-GEMM: C = scale*A*B^T (+bias) ----------------
// A[M,K], B[N,K] bf16 row-major (K contiguous). 128x128 tile, BK=32,
// 4 waves (2x2), each wave 64x64 = 4x4 x (16x16x32 MFMA).
// MODE 0: plain (proj). MODE 1: per-(b,h) attention scores via blockIdx.z.
template<typename CT, bool BIAS, int MODE>
__global__ __launch_bounds__(256)
void gemm_bt(const bf16_t* __restrict__ A, const bf16_t* __restrict__ B,
             const float* __restrict__ bias, CT* __restrict__ C,
             int K, int lda, int ldb, int ldc, float scale)
{
  if (MODE == 1) {
    const int b = blockIdx.z >> 4, h = blockIdx.z & 15;
    const size_t o = (size_t)b * SEQ * D_MODEL + (size_t)h * D_HEAD;
    A += o; B += o;
    C += (size_t)blockIdx.z * SEQ * (size_t)SEQ;
  }
  const int tid = threadIdx.x;
  const int w = tid >> 6, lane = tid & 63;
  const int wr = w >> 1, wc = w & 1;
  const int tM = blockIdx.y * 128, tN = blockIdx.x * 128;

  __shared__ bf16_t As[128*32];
  __shared__ bf16_t Bs[128*32];

  f32x4 acc[4][4] = {};

  // staging: 8KB tile = 8 chunks of 1KB; wave w owns chunks 2w,2w+1
  const int q0 = w*2, q1 = q0+1;
  const int rS = (lane >> 2), cS = (lane & 3) * 8;
  const bf16_t* A0 = A + (size_t)(tM + q0*16 + rS)*lda + cS;
  const bf16_t* A1 = A + (size_t)(tM + q1*16 + rS)*lda + cS;
  const bf16_t* B0 = B + (size_t)(tN + q0*16 + rS)*ldb + cS;
  const bf16_t* B1 = B + (size_t)(tN + q1*16 + rS)*ldb + cS;
  bf16_t* lA0 = As + q0*512; bf16_t* lA1 = As + q1*512;
  bf16_t* lB0 = Bs + q0*512; bf16_t* lB1 = Bs + q1*512;

  const int fr = lane & 15, fk = (lane >> 4) * 8;

  for (int k0 = 0; k0 < K; k0 += 32) {
    gload_lds16(A0 + k0, lA0);
    gload_lds16(A1 + k0, lA1);
    gload_lds16(B0 + k0, lB0);
    gload_lds16(B1 + k0, lB1);
    asm volatile("s_waitcnt vmcnt(0)" ::: "memory");
    __syncthreads();
    bf16x8 af[4], bfm[4];
#pragma unroll
    for (int m = 0; m < 4; m++)
      af[m] = *(const bf16x8*)(As + (wr*64 + m*16 + fr)*32 + fk);
#pragma unroll
    for (int n = 0; n < 4; n++)
      bfm[n] = *(const bf16x8*)(Bs + (wc*64 + n*16 + fr)*32 + fk);
#pragma unroll
    for (int m = 0; m < 4; m++)
#pragma unroll
      for (int n = 0; n < 4; n++)
        acc[m][n] = __builtin_amdgcn_mfma_f32_16x16x32_bf16(af[m], bfm[n], acc[m][n], 0, 0, 0);
    __syncthreads();
  }

  // C/D layout (m89/m91-verified): col = lane&15, row = (lane>>4)*4 + j
  const int fq = (lane >> 4) * 4;
#pragma unroll
  for (int n = 0; n < 4; n++) {
    const int col = tN + wc*64 + n*16 + fr;
    const float bb = BIAS ? bias[col] : 0.f;
#pragma unroll
    for (int m = 0; m < 4; m++) {
#pragma unroll
      for (int j = 0; j < 4; j++) {
        const int row = tM + wr*64 + m*16 + fq + j;
        C[(size_t)row * ldc + col] = (CT)(acc[m][n][j] * scale + bb);
      }
    }
  }
}

// ---------------- per-head V transpose: Vt[z*64+d][i] = V[b*SEQ+i][h*64+d] ----------------
__global__ __launch_bounds__(256)
void transpose_v(const bf16_t* __restrict__ V, bf16_t* __restrict__ Vt) {
  __shared__ bf16_t t[64][72];
  const int z = blockIdx.y, b = z >> 4, h = z & 15;
  const int i0 = blockIdx.x * 64;
  const int tid = threadIdx.x;
  const int r = tid >> 2, c = (tid & 3) * 16;
  const bf16_t* src = V + (size_t)(b*SEQ + i0 + r) * D_MODEL + h*D_HEAD + c;
  *(bf16x8*)&t[r][c]   = *(const bf16x8*)src;
  *(bf16x8*)&t[r][c+8] = *(const bf16x8*)(src + 8);
  __syncthreads();
  bf16x8 o0, o1;
#pragma unroll
  for (int j = 0; j < 8; j++) { o0[j] = t[c+j][r]; o1[j] = t[c+8+j][r]; }
  bf16_t* dst = Vt + (size_t)(z*D_HEAD + r) * SEQ + i0 + c;
  *(bf16x8*)dst = o0;
  *(bf16x8*)(dst + 8) = o1;
}

// ---------------- row softmax in place (one block per row of 2048) ----------------
__global__ __launch_bounds__(256)
void softmax_rows(float* __restrict__ S) {
  float* p = S + (size_t)blockIdx.x * SEQ;
  const int tid = threadIdx.x;
  const int w = tid >> 6, lane = tid & 63;
  f32x4 v0 = *(const f32x4*)(p + tid*8);
  f32x4 v1 = *(const f32x4*)(p + tid*8 + 4);
  float m = v0[0];
#pragma unroll
  for (int j = 1; j < 4; j++) m = fmaxf(m, v0[j]);
#pragma unroll
  for (int j = 0; j < 4; j++) m = fmaxf(m, v1[j]);
  for (int o = 1; o < 64; o <<= 1) m = fmaxf(m, __shfl_xor(m, o, 64));
  __shared__ float red[8];
  if (lane == 0) red[w] = m;
  __syncthreads();
  m = fmaxf(fmaxf(red[0], red[1]), fmaxf(red[2], red[3]));
  float s = 0.f;
#pragma unroll
  for (int j = 0; j < 4; j++) { v0[j] = __expf(v0[j] - m); s += v0[j]; }
#pragma unroll
  for (int j = 0; j < 4; j++) { v1[j] = __expf(v1[j] - m); s += v1[j]; }
  for (int o = 1; o < 64; o <<= 1) s += __shfl_xor(s, o, 64);
  if (lane == 0) red[4 + w] = s;
  __syncthreads();
  s = (red[4] + red[5]) + (red[6] + red[7]);
  const float inv = 1.f / s;
#pragma unroll
  for (int j = 0; j < 4; j++) v0[j] *= inv;
#pragma unroll
  for (int j = 0; j < 4; j++) v1[j] *= inv;
  *(f32x4*)(p + tid*8)     = v0;
  *(f32x4*)(p + tid*8 + 4) = v1;
}

// ---------------- context: C[q,d] = P[q,:] . Vt[d,:]  per (b,h) ----------------
// 128x64 tile, BK=32, 4 waves stacked in M (each 32x64 = 2x4 frags).
// A = attn weights fp32 (converted to bf16 during LDS staging).
__global__ __launch_bounds__(256)
void ctx_gemm(const float* __restrict__ P, const bf16_t* __restrict__ Vt,
              bf16_t* __restrict__ Cb)
{
  const int z = blockIdx.z, b = z >> 4, h = z & 15;
  const float*  Pz = P  + (size_t)z * SEQ * (size_t)SEQ;
  const bf16_t* Bz = Vt + (size_t)z * D_HEAD * SEQ;
  const int tM = blockIdx.y * 128;
  const int tid = threadIdx.x, w = tid >> 6, lane = tid & 63;

  __shared__ bf16_t As[128*32];
  __shared__ bf16_t Bs[64*32];

  f32x4 acc[2][4] = {};

  const int ar = tid >> 1, ac = (tid & 1) * 16;          // A staging: 2 thr/row
  const float* Ap = Pz + (size_t)(tM + ar) * SEQ + ac;
  const int br = w*16 + (lane >> 2), bc = (lane & 3) * 8; // B staging chunk per wave
  const bf16_t* Bp = Bz + (size_t)br * SEQ + bc;
  bf16_t* lB = Bs + w*512;
  const int fr = lane & 15, fk = (lane >> 4) * 8;

  for (int k0 = 0; k0 < SEQ; k0 += 32) {
    gload_lds16(Bp + k0, lB);
    f32x4 u0 = *(const f32x4*)(Ap + k0);
    f32x4 u1 = *(const f32x4*)(Ap + k0 + 4);
    f32x4 u2 = *(const f32x4*)(Ap + k0 + 8);
    f32x4 u3 = *(const f32x4*)(Ap + k0 + 12);
    bf16x8 o0, o1;
    o0[0]=(bf16_t)u0[0]; o0[1]=(bf16_t)u0[1]; o0[2]=(bf16_t)u0[2]; o0[3]=(bf16_t)u0[3];
    o0[4]=(bf16_t)u1[0]; o0[5]=(bf16_t)u1[1]; o0[6]=(bf16_t)u1[2]; o0[7]=(bf16_t)u1[3];
    o1[0]=(bf16_t)u2[0]; o1[1]=(bf16_t)u2[1]; o1[2]=(bf16_t)u2[2]; o1[3]=(bf16_t)u2[3];
    o1[4]=(bf16_t)u3[0]; o1[5]=(bf16_t)u3[1]; o1[6]=(bf16_t)u3[2]; o1[7]=(bf16_t)u3[3];
    *(bf16x8*)(As + ar*32 + ac)     = o0;
    *(bf16x8*)(As + ar*32 + ac + 8) = o1;
    asm volatile("s_waitcnt vmcnt(0)" ::: "memory");
    __syncthreads();
    bf16x8 af[2], bfm[4];
#pragma unroll
    for (int m = 0; m < 2; m++)
      af[m] = *(const bf16x8*)(As + (w*32 + m*16 + fr)*32 + fk);
#pragma unroll
    for (int n = 0; n < 4; n++)
      bfm[n] = *(const bf16x8*)(Bs + (n*16 + fr)*32 + fk);
#pragma unroll
    for (int m = 0; m < 2; m++)
#pragma unroll
      for (int n = 0; n < 4; n++)
        acc[m][n] = __builtin_amdgcn_mfma_f32_16x16x32_bf16(af[m], bfm[n], acc[m][n], 0, 0, 0);
    __syncthreads();
  }

  const int fq = (lane >> 4) * 4;
#pragma unroll
  for (int m = 0; m < 2; m++)
#pragma unroll
    for (int n = 0; n < 4; n++)
#pragma unroll
      for (int j = 0; j < 4; j++) {
        const int row = tM + w*32 + m*16 + fq + j;
        const int col = n*16 + fr;
        Cb[(size_t)(b*SEQ + row) * D_MODEL + h*D_HEAD + col] = (bf16_t)acc[m][n][j];
      }
}

extern "C" void kernel_launch(void* const* d_in, const int* in_sizes, int n_in,
                              void* d_out, int out_size, void* d_ws, size_t ws_size,
                              hipStream_t stream) {
  (void)in_sizes; (void)n_in; (void)out_size; (void)ws_size;
  const float* x  = (const float*)d_in[0];
  const float* Wq = (const float*)d_in[1];
  const float* bq = (const float*)d_in[2];
  const float* Wk = (const float*)d_in[3];
  const float* bk = (const float*)d_in[4];
  const float* Wv = (const float*)d_in[5];
  const float* bv = (const float*)d_in[6];
  const float* Wo = (const float*)d_in[7];
  const float* bo = (const float*)d_in[8];

  bf16_t* p   = (bf16_t*)d_ws;
  bf16_t* xb  = p; p += (size_t)ROWS*D_MODEL;
  bf16_t* Wqb = p; p += (size_t)D_MODEL*D_MODEL;
  bf16_t* Wkb = p; p += (size_t)D_MODEL*D_MODEL;
  bf16_t* Wvb = p; p += (size_t)D_MODEL*D_MODEL;
  bf16_t* Wob = p; p += (size_t)D_MODEL*D_MODEL;
  bf16_t* Qb  = p; p += (size_t)ROWS*D_MODEL;
  bf16_t* Kb  = p; p += (size_t)ROWS*D_MODEL;
  bf16_t* Vb  = p; p += (size_t)ROWS*D_MODEL;
  bf16_t* Vtb = p; p += (size_t)ROWS*D_MODEL;  // [BH*64][SEQ]
  bf16_t* Cb  = p;                              // context bf16 [ROWS][D_MODEL]

  float* out0 = (float*)d_out;
  float* attn = out0 + (size_t)ROWS*D_MODEL;    // [BH][SEQ][SEQ] fp32

  cvt_bf16<<<2048, 256, 0, stream>>>(x,  xb,  ROWS*D_MODEL/8);
  cvt_bf16<<<512,  256, 0, stream>>>(Wq, Wqb, D_MODEL*D_MODEL/8);
  cvt_bf16<<<512,  256, 0, stream>>>(Wk, Wkb, D_MODEL*D_MODEL/8);
  cvt_bf16<<<512,  256, 0, stream>>>(Wv, Wvb, D_MODEL*D_MODEL/8);
  cvt_bf16<<<512,  256, 0, stream>>>(Wo, Wob, D_MODEL*D_MODEL/8);

  // Q/K/V projections: [4096,1024] = xb * W^T + b
  gemm_bt<bf16_t, true, 0><<<dim3(8,32,1), 256, 0, stream>>>(xb, Wqb, bq, Qb, D_MODEL, D_MODEL, D_MODEL, D_MODEL, 1.f);
  gemm_bt<bf16_t, true, 0><<<dim3(8,32,1), 256, 0, stream>>>(xb, Wkb, bk, Kb, D_MODEL, D_MODEL, D_MODEL, D_MODEL, 1.f);
  gemm_bt<bf16_t, true, 0><<<dim3(8,32,1), 256, 0, stream>>>(xb, Wvb, bv, Vb, D_MODEL, D_MODEL, D_MODEL, D_MODEL, 1.f);

  transpose_v<<<dim3(SEQ/64, BH), 256, 0, stream>>>(Vb, Vtb);

  // raw scores -> attn region of d_out (scale 1/sqrt(64))
  gemm_bt<float, false, 1><<<dim3(16,16,BH), 256, 0, stream>>>(Qb, Kb, nullptr, attn, D_HEAD, D_MODEL, D_MODEL, SEQ, 0.125f);

  softmax_rows<<<BH*SEQ, 256, 0, stream>>>(attn);

  ctx_gemm<<<dim3(1,16,BH), 256, 0, stream>>>(attn, Vtb, Cb);

  // output projection -> first 4,194,304 floats of d_out
  gemm_bt<float, true, 0><<<dim3(8,32,1), 256, 0, stream>>>(Cb, Wob, bo, out0, D_MODEL, D_MODEL, D_MODEL, D_MODEL, 1.f);
}

// Round 2
// 789.217 us; speedup vs baseline: 1.4066x; 1.4066x over previous
//
#include <hip/hip_runtime.h>
#include <hip/hip_bf16.h>
#include <cstdint>

#define D_MODEL 1024
#define N_HEADS 16
#define D_HEAD  64
#define SEQ     2048
#define ROWS    4096
#define BH      32
#define QKVN    3072
#define KT      128   // attention k-tile
#define QT      64    // attention q-rows per block

typedef __bf16 bf16_t;
typedef __bf16 bf16x8 __attribute__((ext_vector_type(8)));
typedef float  f32x4  __attribute__((ext_vector_type(4)));

// async global->LDS, 16B per lane; LDS dest wave-uniform base (HW adds lane*16)
__device__ __forceinline__ void gload_lds16(const void* g, void* l) {
  __builtin_amdgcn_global_load_lds(
      (__attribute__((address_space(1))) void*)const_cast<void*>(g),
      (__attribute__((address_space(3))) void*)l, 16, 0, 0);
}

// ---------------- fp32 -> bf16 elementwise (8/thread) ----------------
__global__ __launch_bounds__(256)
void cvt_bf16(const float* __restrict__ in, bf16_t* __restrict__ out, int n8) {
  int i = blockIdx.x * 256 + threadIdx.x;
  if (i >= n8) return;
  const f32x4* src = (const f32x4*)in + (size_t)i * 2;
  f32x4 a = src[0], b = src[1];
  bf16x8 o;
  o[0]=(bf16_t)a[0]; o[1]=(bf16_t)a[1]; o[2]=(bf16_t)a[2]; o[3]=(bf16_t)a[3];
  o[4]=(bf16_t)b[0]; o[5]=(bf16_t)b[1]; o[6]=(bf16_t)b[2]; o[7]=(bf16_t)b[3];
  ((bf16x8*)out)[i] = o;
}

__global__ __launch_bounds__(256)
void concat_bias(const float* __restrict__ bq, const float* __restrict__ bk,
                 const float* __restrict__ bv, float* __restrict__ o) {
  int i = blockIdx.x * 256 + threadIdx.x;
  if (i < 1024) o[i] = bq[i];
  else if (i < 2048) o[i] = bk[i - 1024];
  else if (i < 3072) o[i] = bv[i - 2048];
}

// ---------------- bt-GEMM: C = scale*A*B^T (+bias), 128x128 tile ----------------
template<typename CT, bool BIAS>
__global__ __launch_bounds__(256)
void gemm_bt(const bf16_t* __restrict__ A, const bf16_t* __restrict__ B,
             const float* __restrict__ bias, CT* __restrict__ C,
             int K, int lda, int ldb, int ldc, float scale)
{
  const int tid = threadIdx.x;
  const int w = tid >> 6, lane = tid & 63;
  const int wr = w >> 1, wc = w & 1;
  const int tM = blockIdx.y * 128, tN = blockIdx.x * 128;

  __shared__ bf16_t As[128*32];
  __shared__ bf16_t Bs[128*32];

  f32x4 acc[4][4] = {};

  const int q0 = w*2, q1 = q0+1;
  const int rS = (lane >> 2), cS = (lane & 3) * 8;
  const bf16_t* A0 = A + (size_t)(tM + q0*16 + rS)*lda + cS;
  const bf16_t* A1 = A + (size_t)(tM + q1*16 + rS)*lda + cS;
  const bf16_t* B0 = B + (size_t)(tN + q0*16 + rS)*ldb + cS;
  const bf16_t* B1 = B + (size_t)(tN + q1*16 + rS)*ldb + cS;
  bf16_t* lA0 = As + q0*512; bf16_t* lA1 = As + q1*512;
  bf16_t* lB0 = Bs + q0*512; bf16_t* lB1 = Bs + q1*512;

  const int fr = lane & 15, fk = (lane >> 4) * 8;

  for (int k0 = 0; k0 < K; k0 += 32) {
    gload_lds16(A0 + k0, lA0);
    gload_lds16(A1 + k0, lA1);
    gload_lds16(B0 + k0, lB0);
    gload_lds16(B1 + k0, lB1);
    asm volatile("s_waitcnt vmcnt(0)" ::: "memory");
    __syncthreads();
    bf16x8 af[4], bfm[4];
#pragma unroll
    for (int m = 0; m < 4; m++)
      af[m] = *(const bf16x8*)(As + (wr*64 + m*16 + fr)*32 + fk);
#pragma unroll
    for (int n = 0; n < 4; n++)
      bfm[n] = *(const bf16x8*)(Bs + (wc*64 + n*16 + fr)*32 + fk);
#pragma unroll
    for (int m = 0; m < 4; m++)
#pragma unroll
      for (int n = 0; n < 4; n++)
        acc[m][n] = __builtin_amdgcn_mfma_f32_16x16x32_bf16(af[m], bfm[n], acc[m][n], 0, 0, 0);
    __syncthreads();
  }

  const int fq = (lane >> 4) * 4;
#pragma unroll
  for (int n = 0; n < 4; n++) {
    const int col = tN + wc*64 + n*16 + fr;
    const float bb = BIAS ? bias[col] : 0.f;
#pragma unroll
    for (int m = 0; m < 4; m++) {
#pragma unroll
      for (int j = 0; j < 4; j++) {
        const int row = tM + wr*64 + m*16 + fq + j;
        C[(size_t)row * ldc + col] = (CT)(acc[m][n][j] * scale + bb);
      }
    }
  }
}

// ------- per-head V transpose from fused QKV: Vt[z*64+d][i] = QKV[b*SEQ+i][2048+h*64+d] -------
__global__ __launch_bounds__(256)
void transpose_v(const bf16_t* __restrict__ QKV, bf16_t* __restrict__ Vt) {
  __shared__ bf16_t t[64][72];
  const int z = blockIdx.y, b = z >> 4, h = z & 15;
  const int i0 = blockIdx.x * 64;
  const int tid = threadIdx.x;
  const int r = tid >> 2, c = (tid & 3) * 16;
  const bf16_t* src = QKV + (size_t)(b*SEQ + i0 + r) * QKVN + 2048 + h*D_HEAD + c;
  *(bf16x8*)&t[r][c]   = *(const bf16x8*)src;
  *(bf16x8*)&t[r][c+8] = *(const bf16x8*)(src + 8);
  __syncthreads();
  bf16x8 o0, o1;
#pragma unroll
  for (int j = 0; j < 8; j++) { o0[j] = t[c+j][r]; o1[j] = t[c+8+j][r]; }
  bf16_t* dst = Vt + (size_t)(z*D_HEAD + r) * SEQ + i0 + c;
  *(bf16x8*)dst = o0;
  *(bf16x8*)(dst + 8) = o1;
}

// ---------------- fused attention: two-pass flash with recompute ----------------
// Block: (qtile of 64 rows, z=(b,h)). 4 waves, wave w owns q-rows [w*16, w*16+16).
// Loop1 (t=0..15): QK^T per 128-k tile, online (m,l) per row (scalar rescale only).
// Loop2 (t=16..31): recompute S, P=exp(s*scale-m)/l -> write fp32 P (attn out) +
//                   bf16 P to wave-private swizzled LDS -> PV MFMA accumulate.
// LDS tiles XOR-swizzled (chunk ^= row&7) with pre-swizzled global sources.
__global__ __launch_bounds__(256, 2)
void attn_fused(const bf16_t* __restrict__ QKV, const bf16_t* __restrict__ Vt,
                float* __restrict__ Pout, bf16_t* __restrict__ Cb)
{
  const int z = blockIdx.y, b = z >> 4, h = z & 15;
  const int q0 = blockIdx.x * QT;
  const int tid = threadIdx.x, w = tid >> 6, lane = tid & 63;
  const int fr = lane & 15, g4 = lane >> 4;

  __shared__ bf16_t Ks[2][KT*64];    // [k][d], swizzled, 16KB each
  __shared__ bf16_t Vs[2][64*KT];    // [d][k], swizzled, 16KB each
  __shared__ bf16_t Ps[4][16*KT];    // per-wave [q][k], swizzled, 4KB each

  // Q fragments (A-operand): lane&15 = q row, (lane>>4)*8 + kk*32 = d
  const bf16_t* Qrow = QKV + (size_t)(b*SEQ + q0 + w*16 + fr) * QKVN + h*D_HEAD;
  bf16x8 qf0 = *(const bf16x8*)(Qrow + g4*8);
  bf16x8 qf1 = *(const bf16x8*)(Qrow + 32 + g4*8);

  const bf16_t* Kbase  = QKV + (size_t)(b*SEQ)*QKVN + D_MODEL + h*D_HEAD; // + k*QKVN
  const bf16_t* Vtbase = Vt + (size_t)z * D_HEAD * SEQ;                    // + d*SEQ
  float* Pz = Pout + (size_t)z * SEQ * SEQ;

  const int kr = lane >> 3, kc = lane & 7;    // K staging: 8 rows x 8 chunks
  const int vr = lane >> 4, vc = lane & 15;   // V staging: 4 rows x 16 chunks

  auto STAGE_K = [&](int kt, int buf) {
#pragma unroll
    for (int g = 0; g < 4; g++) {
      const int row = w*32 + g*8 + kr;          // row&7 == kr
      gload_lds16(Kbase + (size_t)(kt*KT + row)*QKVN + ((kc ^ kr) * 8),
                  &Ks[buf][(w*32 + g*8)*64]);
    }
  };
  auto STAGE_V = [&](int kt, int buf) {
#pragma unroll
    for (int g = 0; g < 4; g++) {
      const int drow = w*16 + g*4 + vr;
      gload_lds16(Vtbase + (size_t)drow*SEQ + kt*KT + (((vc ^ (drow & 7)) & 15) * 8),
                  &Vs[buf][(w*16 + g*4)*KT]);
    }
  };

  float m[4], l[4], invl[4];
#pragma unroll
  for (int j = 0; j < 4; j++) { m[j] = -1e30f; l[j] = 0.f; invl[j] = 0.f; }
  f32x4 oacc[4] = {};

  STAGE_K(0, 0);
  asm volatile("s_waitcnt vmcnt(0)" ::: "memory");
  __syncthreads();

  const int qrow_g = q0 + w*16;   // wave's global q base

  for (int t = 0; t < 32; t++) {
    const int buf = t & 1;
    const int kt  = t & 15;

    // prefetch next tile into the other buffer
    if (t < 31) {
      const int ktn = (t + 1) & 15;
      STAGE_K(ktn, buf ^ 1);
      if (t + 1 >= 16) STAGE_V(ktn, buf ^ 1);
    }

    // ---- QK^T: 8 frags of 16 cols, contraction d=64 (2 MFMAs each) ----
    f32x4 sc[8] = {};
#pragma unroll
    for (int f = 0; f < 8; f++) {
      const int krow = f*16 + fr;
      const int swz = krow & 7;
      const bf16_t* kp = &Ks[buf][krow*64];
      bf16x8 kf0 = *(const bf16x8*)(kp + ((g4 ^ swz) * 8));
      bf16x8 kf1 = *(const bf16x8*)(kp + (((4 + g4) ^ swz) * 8));
      sc[f] = __builtin_amdgcn_mfma_f32_16x16x32_bf16(qf0, kf0, sc[f], 0, 0, 0);
      sc[f] = __builtin_amdgcn_mfma_f32_16x16x32_bf16(qf1, kf1, sc[f], 0, 0, 0);
    }

    if (t < 16) {
      // ---- online (m,l) update, rows = g4*4+j ----
      float tmax[4], ts[4];
#pragma unroll
      for (int j = 0; j < 4; j++) tmax[j] = sc[0][j];
#pragma unroll
      for (int f = 1; f < 8; f++)
#pragma unroll
        for (int j = 0; j < 4; j++) tmax[j] = fmaxf(tmax[j], sc[f][j]);
#pragma unroll
      for (int o = 1; o < 16; o <<= 1)
#pragma unroll
        for (int j = 0; j < 4; j++) tmax[j] = fmaxf(tmax[j], __shfl_xor(tmax[j], o, 64));
      float mn[4];
#pragma unroll
      for (int j = 0; j < 4; j++) { mn[j] = fmaxf(m[j], tmax[j] * 0.125f); ts[j] = 0.f; }
#pragma unroll
      for (int f = 0; f < 8; f++)
#pragma unroll
        for (int j = 0; j < 4; j++) ts[j] += __expf(fmaf(sc[f][j], 0.125f, -mn[j]));
#pragma unroll
      for (int o = 1; o < 16; o <<= 1)
#pragma unroll
        for (int j = 0; j < 4; j++) ts[j] += __shfl_xor(ts[j], o, 64);
#pragma unroll
      for (int j = 0; j < 4; j++) {
        l[j] = l[j] * __expf(m[j] - mn[j]) + ts[j];
        m[j] = mn[j];
      }
      if (t == 15)
#pragma unroll
        for (int j = 0; j < 4; j++) invl[j] = 1.f / l[j];
    } else {
      // ---- P = exp(s*scale - m) * invl: write fp32 global + bf16 LDS ----
      const int k0 = kt * KT;
#pragma unroll
      for (int f = 0; f < 8; f++) {
        const int k_l = f*16 + fr;
#pragma unroll
        for (int j = 0; j < 4; j++) {
          const float p = __expf(fmaf(sc[f][j], 0.125f, -m[j])) * invl[j];
          const int q_l = g4*4 + j;
          Pz[(size_t)(qrow_g + q_l) * SEQ + k0 + k_l] = p;
          Ps[w][q_l*128 + ((((k_l >> 3) ^ (q_l & 7)) << 3) | (k_l & 7))] = (bf16_t)p;
        }
      }
      // ---- PV: O[q][d] += P[q][k] * Vt[d][k], contraction k=128 (4 MFMAs/frag) ----
#pragma unroll
      for (int kk = 0; kk < 4; kk++) {
        const int chunk = kk*4 + g4;
        bf16x8 pa = *(const bf16x8*)(&Ps[w][fr*128 + ((chunk ^ (fr & 7)) << 3)]);
#pragma unroll
        for (int n = 0; n < 4; n++) {
          const int drow = n*16 + fr;
          bf16x8 vf = *(const bf16x8*)(&Vs[buf][drow*128 + ((chunk ^ (drow & 7)) << 3)]);
          oacc[n] = __builtin_amdgcn_mfma_f32_16x16x32_bf16(pa, vf, oacc[n], 0, 0, 0);
        }
      }
    }

    asm volatile("s_waitcnt vmcnt(0)" ::: "memory");
    __syncthreads();
  }

  // ---- context write (bf16): col = n*16+fr (d), row = g4*4+j ----
#pragma unroll
  for (int n = 0; n < 4; n++)
#pragma unroll
    for (int j = 0; j < 4; j++)
      Cb[(size_t)(b*SEQ + qrow_g + g4*4 + j) * D_MODEL + h*D_HEAD + n*16 + fr] =
          (bf16_t)oacc[n][j];
}

extern "C" void kernel_launch(void* const* d_in, const int* in_sizes, int n_in,
                              void* d_out, int out_size, void* d_ws, size_t ws_size,
                              hipStream_t stream) {
  (void)in_sizes; (void)n_in; (void)out_size; (void)ws_size;
  const float* x  = (const float*)d_in[0];
  const float* Wq = (const float*)d_in[1];
  const float* bq = (const float*)d_in[2];
  const float* Wk = (const float*)d_in[3];
  const float* bk = (const float*)d_in[4];
  const float* Wv = (const float*)d_in[5];
  const float* bv = (const float*)d_in[6];
  const float* Wo = (const float*)d_in[7];
  const float* bo = (const float*)d_in[8];

  bf16_t* p    = (bf16_t*)d_ws;
  bf16_t* xb   = p; p += (size_t)ROWS*D_MODEL;
  bf16_t* Wqkv = p; p += (size_t)3*D_MODEL*D_MODEL;  // Wq|Wk|Wv contiguous
  bf16_t* Wob  = p; p += (size_t)D_MODEL*D_MODEL;
  bf16_t* QKVb = p; p += (size_t)ROWS*QKVN;
  bf16_t* Vtb  = p; p += (size_t)BH*D_HEAD*SEQ;
  bf16_t* Cb   = p; p += (size_t)ROWS*D_MODEL;
  float*  bias3 = (float*)p;

  float* out0 = (float*)d_out;
  float* attn = out0 + (size_t)ROWS*D_MODEL;    // [BH][SEQ][SEQ] fp32

  cvt_bf16<<<2048, 256, 0, stream>>>(x,  xb,  ROWS*D_MODEL/8);
  cvt_bf16<<<512,  256, 0, stream>>>(Wq, Wqkv,                     D_MODEL*D_MODEL/8);
  cvt_bf16<<<512,  256, 0, stream>>>(Wk, Wqkv + D_MODEL*D_MODEL,   D_MODEL*D_MODEL/8);
  cvt_bf16<<<512,  256, 0, stream>>>(Wv, Wqkv + 2*D_MODEL*D_MODEL, D_MODEL*D_MODEL/8);
  cvt_bf16<<<512,  256, 0, stream>>>(Wo, Wob,                      D_MODEL*D_MODEL/8);
  concat_bias<<<12, 256, 0, stream>>>(bq, bk, bv, bias3);

  // fused QKV projection: [4096,3072] = xb * [Wq|Wk|Wv]^T + bias3
  gemm_bt<bf16_t, true><<<dim3(24, 32), 256, 0, stream>>>(
      xb, Wqkv, bias3, QKVb, D_MODEL, D_MODEL, D_MODEL, QKVN, 1.f);

  transpose_v<<<dim3(SEQ/64, BH), 256, 0, stream>>>(QKVb, Vtb);

  attn_fused<<<dim3(SEQ/QT, BH), 256, 0, stream>>>(QKVb, Vtb, attn, Cb);

  // output projection
  gemm_bt<float, true><<<dim3(8, 32), 256, 0, stream>>>(
      Cb, Wob, bo, out0, D_MODEL, D_MODEL, D_MODEL, D_MODEL, 1.f);
}